// Round 13
// baseline (22036.029 us; speedup 1.0000x reference)
//
#include <hip/hip_runtime.h>

// 2-layer stacked LSTM (shared cell), B=256, T=1024, F=UNITS=128 — MFMA v10.
// N-SPLIT: 256 LSTM WGs (256 thr, 4 waves). WG pair (g, g+128) shares batch
// group g (2 batches); half h = wg>>7 owns units [64h, 64h+64). Per-WG MFMA
// halves to 128/tick (621 cyc floor); trans/LDS per SIMD halve too.
// Cross-WG h-exchange per tick via L2 (512B packed f16, flag-gated,
// device-scope atomics). K-slices (kt) of the A-tiles align exactly with
// column ownership: phase1 = own-kt MFMAs (hides partner fetch), barrier,
// phase2 = partner-kt MFMAs + v5-style trans splicing.
// Flags/acks in d_ws (zeroed at kernel start -> replay-safe); exchange data
// in the tail of the zeros output region, re-zeroed by owner after a
// reader-ack handshake (validation sees zeros).
// Blocks 256..511 fill the rest of the zeros output.
//
// d_out (f32): [0,32768) h2_final | [32768,+33554432) zeros | [33587200,..) c1

typedef _Float16 f16;
typedef _Float16 f16x2 __attribute__((ext_vector_type(2)));
typedef _Float16 f16x8 __attribute__((ext_vector_type(8)));
typedef float    f32x4 __attribute__((ext_vector_type(4)));

#define T_STEPS 1024
#define UNITS   128
#define NLSTM   256
#define NBLK    512
#define OUT_ZERO 32768
#define OUT_C1   33587200
#define TILEB   4096
#define ZTOT_F   33554432u
#define EXCH_DW  65536u                      // 256 WGs * 2 slots * 128 dwords
#define ZFILL_F4 ((ZTOT_F - EXCH_DW) / 4)    // 8372224 float4s for zero-blocks

#define MFMA16(A,B,C) __builtin_amdgcn_mfma_f32_16x16x32_f16((A),(B),(C),0,0,0)

__device__ __forceinline__ float frcp_(float x) {
#if __has_builtin(__builtin_amdgcn_rcpf)
    return __builtin_amdgcn_rcpf(x);
#else
    return 1.0f / x;
#endif
}
__device__ __forceinline__ float sigmoidf_(float x) { return frcp_(1.0f + __expf(-x)); }
__device__ __forceinline__ float tanhf_(float x) {
    float e = __expf(2.0f * x);
    return 1.0f - 2.0f * frcp_(e + 1.0f);
}
__device__ __forceinline__ unsigned pkh(float a, float b) {
    f16x2 t; t[0] = (f16)a; t[1] = (f16)b;
    return __builtin_bit_cast(unsigned, t);
}
__device__ __forceinline__ int swb(int row, int byteoff) {
    return row * 256 + (byteoff ^ ((row & 7) << 4));
}

__global__ __launch_bounds__(256, 2) void lstm2_kernel(
    const float* __restrict__ X,   // [256][1024][128]
    const float* __restrict__ W,   // [128][512] gate order i|f|g|o
    const float* __restrict__ U,   // [128][512]
    const float* __restrict__ Bv,  // [512]
    float* __restrict__ out,
    int* __restrict__ flags)       // d_ws: [0..256) tick flags, [256..512) acks
{
    const int blk = blockIdx.x;
    const int tid = threadIdx.x;

    if (blk >= NLSTM) {
        // ---------- zeros-output fill (excluding the exchange tail) ----------
        const size_t nthr = (size_t)(NBLK - NLSTM) * 256;
        float4* dst = (float4*)(out + OUT_ZERO);
        const float4 z4 = make_float4(0.f, 0.f, 0.f, 0.f);
        for (size_t i = (size_t)(blk - NLSTM) * 256 + tid; i < ZFILL_F4; i += nthr)
            dst[i] = z4;
        return;
    }

    // ---------- LSTM workgroup ----------
    const int wg = blk, grp = wg & 127, half = wg >> 7, pwg = wg ^ 128;
    if (tid == 0) {   // reset own sync words early (replay/poison-safe)
        __hip_atomic_store(&flags[wg],       0, __ATOMIC_RELAXED, __HIP_MEMORY_SCOPE_AGENT);
        __hip_atomic_store(&flags[256 + wg], 0, __ATOMIC_RELAXED, __HIP_MEMORY_SCOPE_AGENT);
    }
    const int w  = tid >> 6;            // wave = unit sub-block
    const int l  = tid & 63;
    const int lr = l & 15;              // A row / C col (unit within block)
    const int lc = l >> 4;              // k-sub / batch row (lc<2 valid)
    const int u  = half * 64 + w * 16 + lr;   // absolute unit
    const int b0 = grp * 2;
    unsigned* exch = (unsigned*)(out + OUT_ZERO + (ZTOT_F - EXCH_DW));

    __shared__ __align__(16) char A1t[2][TILEB];   // [x ; h1] interleaved rows
    __shared__ __align__(16) char A2t[2][TILEB];   // [h1 ; h2]
    char* A1base = &A1t[0][0];
    char* A2base = &A2t[0][0];

    // ---- weight B-fragments (full K, own 64 units' gate cols)
    f16x8 Wf[4][4], Uf[4][4];
    #pragma unroll
    for (int g = 0; g < 4; ++g)
        #pragma unroll
        for (int kt = 0; kt < 4; ++kt) {
            f16x8 wt, ut;
            #pragma unroll
            for (int j = 0; j < 8; ++j) {
                const int krow = kt * 32 + lc * 8 + j;
                wt[j] = (f16)W[(size_t)krow * 512 + g * 128 + u];
                ut[j] = (f16)U[(size_t)krow * 512 + g * 128 + u];
            }
            Wf[g][kt] = wt;  Uf[g][kt] = ut;
        }
    float bias[4];
    #pragma unroll
    for (int g = 0; g < 4; ++g) bias[g] = Bv[g * 128 + u];

    int raddr[4];
    #pragma unroll
    for (int kt = 0; kt < 4; ++kt) raddr[kt] = swb(lr, kt * 64 + lc * 16);
    const int ka0 = half * 2, ka1 = ka0 + 1;       // own k-slices (own cols)
    const int kb0 = ka0 ^ 2,  kb1 = kb0 + 1;       // partner k-slices

    // ---- init: zero tiles; x(0) -> A1 buf0 rows {0,4}
    for (int i = tid; i < 2 * TILEB / 4; i += 256) {
        ((float*)A1base)[i] = 0.0f;
        ((float*)A2base)[i] = 0.0f;
    }
    __syncthreads();
    if (tid < 128) {
        const int a = tid >> 6, c = (tid & 63) * 2;
        const float2 v = *(const float2*)(X + (size_t)(b0 + a) * (T_STEPS * UNITS) + c);
        *(unsigned*)(A1base + swb(4 * a, c * 2)) = pkh(v.x, v.y);
    }
    __syncthreads();

    float c1 = 0.f, c2 = 0.f;

    for (int k = 0; k <= T_STEPS; ++k) {
        const int rdo = (k & 1) * TILEB, wro = TILEB - rdo;
        char* A1r = A1base + rdo;  char* A1w = A1base + wro;
        char* A2r = A2base + rdo;  char* A2w = A2base + wro;

        // x(k+1) prefetch
        float xa = 0.f, xb = 0.f;
        const bool ldx = (tid < 128) && (k + 1 < T_STEPS);
        if (ldx) {
            const float2 v = *(const float2*)(X + (size_t)(b0 + (tid >> 6)) * (T_STEPS * UNITS)
                                                + (size_t)(k + 1) * UNITS + (tid & 63) * 2);
            xa = v.x; xb = v.y;
        }

        // ---- phase B: own-kt A fragments
        f16x8 A1a0 = *(const f16x8*)(A1r + raddr[ka0]);
        f16x8 A1a1 = *(const f16x8*)(A1r + raddr[ka1]);
        f16x8 A2a0 = *(const f16x8*)(A2r + raddr[ka0]);
        f16x8 A2a1 = *(const f16x8*)(A2r + raddr[ka1]);

        // ---- phase C: 16 MFMA over own k-slices (ILP4)
        f32x4 accI = {bias[0], bias[0], bias[0], bias[0]};
        f32x4 accF = {bias[1], bias[1], bias[1], bias[1]};
        f32x4 accG = {bias[2], bias[2], bias[2], bias[2]};
        f32x4 accO = {bias[3], bias[3], bias[3], bias[3]};
        accI = MFMA16(A1a0, Wf[0][ka0], accI);  accF = MFMA16(A1a0, Wf[1][ka0], accF);
        accG = MFMA16(A1a0, Wf[2][ka0], accG);  accO = MFMA16(A1a0, Wf[3][ka0], accO);
        accI = MFMA16(A1a1, Wf[0][ka1], accI);  accF = MFMA16(A1a1, Wf[1][ka1], accF);
        accG = MFMA16(A1a1, Wf[2][ka1], accG);  accO = MFMA16(A1a1, Wf[3][ka1], accO);
        accI = MFMA16(A2a0, Uf[0][ka0], accI);  accF = MFMA16(A2a0, Uf[1][ka0], accF);
        accG = MFMA16(A2a0, Uf[2][ka0], accG);  accO = MFMA16(A2a0, Uf[3][ka0], accO);
        accI = MFMA16(A2a1, Uf[0][ka1], accI);  accF = MFMA16(A2a1, Uf[1][ka1], accF);
        accG = MFMA16(A2a1, Uf[2][ka1], accG);  accO = MFMA16(A2a1, Uf[3][ka1], accO);

        // ---- partner fetch (spins under the MFMA shadow)
        unsigned pd = 0;
        if (k > 0) {
            while (__hip_atomic_load(&flags[pwg], __ATOMIC_ACQUIRE, __HIP_MEMORY_SCOPE_AGENT) < k)
                __builtin_amdgcn_s_sleep(8);
            if (tid < 128)
                pd = exch[(size_t)pwg * 256 + (size_t)((k - 1) & 1) * 128 + tid];
        }
        // ---- phase D: partner h -> READ tiles (partner columns only)
        if (k > 0 && tid < 128) {
            const int a = tid >> 6, pu = (half ^ 1) * 64 + (tid & 63);
            const unsigned short h1b = (unsigned short)(pd & 0xffffu);
            const unsigned short h2b = (unsigned short)(pd >> 16);
            *(unsigned short*)(A1r + swb(4 * a + 1, pu * 2)) = h1b;
            *(unsigned short*)(A2r + swb(4 * a,     pu * 2)) = h1b;
            *(unsigned short*)(A2r + swb(4 * a + 1, pu * 2)) = h2b;
        }
        __syncthreads();
        if (k > 0 && tid == 0)   // reader-ack: h(k-1) consumed
            __hip_atomic_store(&flags[256 + wg], k, __ATOMIC_RELEASE, __HIP_MEMORY_SCOPE_AGENT);

        // ---- phase E: partner-kt fragments
        f16x8 A1b0 = *(const f16x8*)(A1r + raddr[kb0]);
        f16x8 A1b1 = *(const f16x8*)(A1r + raddr[kb1]);
        f16x8 A2b0 = *(const f16x8*)(A2r + raddr[kb0]);
        f16x8 A2b1 = *(const f16x8*)(A2r + raddr[kb1]);

        // ---- phase F: g,o finish first (ILP2), then i,f with splices
        accG = MFMA16(A1b0, Wf[2][kb0], accG);  accO = MFMA16(A1b0, Wf[3][kb0], accO);
        accG = MFMA16(A1b1, Wf[2][kb1], accG);  accO = MFMA16(A1b1, Wf[3][kb1], accO);
        accG = MFMA16(A2b0, Uf[2][kb0], accG);  accO = MFMA16(A2b0, Uf[3][kb0], accO);
        accG = MFMA16(A2b1, Uf[2][kb1], accG);  accO = MFMA16(A2b1, Uf[3][kb1], accO);
        float gg0, gg1, oo0, oo1;
        accI = MFMA16(A1b0, Wf[0][kb0], accI);  accF = MFMA16(A1b0, Wf[1][kb0], accF);
        gg0 = tanhf_(accG[0]);
        accI = MFMA16(A1b1, Wf[0][kb1], accI);  accF = MFMA16(A1b1, Wf[1][kb1], accF);
        oo0 = sigmoidf_(accO[0]);
        accI = MFMA16(A2b0, Uf[0][kb0], accI);  accF = MFMA16(A2b0, Uf[1][kb0], accF);
        gg1 = tanhf_(accG[1]);
        accI = MFMA16(A2b1, Uf[0][kb1], accI);  accF = MFMA16(A2b1, Uf[1][kb1], accF);
        oo1 = sigmoidf_(accO[1]);

        // ---- tail: e=0 cell1 step k, e=1 cell2 step k-1
        const bool act1 = (k < T_STEPS), act2 = (k > 0);
        const float si0 = sigmoidf_(accI[0]), si1 = sigmoidf_(accI[1]);
        const float sf0 = sigmoidf_(accF[0]), sf1 = sigmoidf_(accF[1]);
        const float cn1 = sf0 * c1 + si0 * gg0;
        const float cn2 = sf1 * c2 + si1 * gg1;
        if (act1) c1 = cn1;
        if (act2) c2 = cn2;
        const float h1v = oo0 * tanhf_(cn1);
        const float h2v = act2 ? (oo1 * tanhf_(cn2)) : 0.0f;

        // ---- own-column h writes + exchange write + final outputs
        if (lc < 2) {
            if (act1) {
                *(f16*)(A1w + swb(4 * lc + 1, u * 2)) = (f16)h1v;
                *(f16*)(A2w + swb(4 * lc,     u * 2)) = (f16)h1v;
            }
            if (act1 && act2)
                *(f16*)(A2w + swb(4 * lc + 1, u * 2)) = (f16)h2v;
            if (k < T_STEPS)
                exch[(size_t)wg * 256 + (size_t)(k & 1) * 128 + lc * 64 + w * 16 + lr] = pkh(h1v, h2v);
            if (k == T_STEPS - 1) out[OUT_C1 + (size_t)(b0 + lc) * UNITS + u] = c1;
            if (k == T_STEPS)     out[(size_t)(b0 + lc) * UNITS + u] = h2v;
        }
        if (ldx)
            *(unsigned*)(A1w + swb(4 * (tid >> 6), (tid & 63) * 4)) = pkh(xa, xb);

        __syncthreads();
        if (k < T_STEPS && tid == 0)   // publish h(k)
            __hip_atomic_store(&flags[wg], k + 1, __ATOMIC_RELEASE, __HIP_MEMORY_SCOPE_AGENT);
    }

    // ---- exit: wait until partner consumed our last h, then zero our
    //      exchange slots (they live inside the validated zeros output)
    while (__hip_atomic_load(&flags[256 + pwg], __ATOMIC_ACQUIRE, __HIP_MEMORY_SCOPE_AGENT) < T_STEPS)
        __builtin_amdgcn_s_sleep(8);
    exch[(size_t)wg * 256 + tid] = 0;
}

extern "C" void kernel_launch(void* const* d_in, const int* in_sizes, int n_in,
                              void* d_out, int out_size, void* d_ws, size_t ws_size,
                              hipStream_t stream) {
    const float* X  = (const float*)d_in[0];
    const float* W  = (const float*)d_in[1];
    const float* U  = (const float*)d_in[2];
    const float* Bv = (const float*)d_in[3];
    float* out = (float*)d_out;
    int* flags = (int*)d_ws;   // needs 2 KiB
    hipLaunchKernelGGL(lstm2_kernel, dim3(NBLK), dim3(256), 0, stream,
                       X, W, U, Bv, out, flags);
}

// Round 14
// 19631.845 us; speedup vs baseline: 1.1225x; 1.1225x over previous
//
#include <hip/hip_runtime.h>

// 2-layer stacked LSTM (shared cell), B=256, T=1024, F=UNITS=128 — MFMA v10b.
// = v10 (N-split across WG pairs, validated-correct) with the rule-#20 fix:
//   K-slices are PERMUTED per WG so own slices = local idx {0,1}, partner
//   slices = local idx {2,3}. All Wf/Uf/raddr accesses use literal constant
//   indices (v10's runtime ka0/kb0 indexing spilled 128 weight VGPRs to
//   scratch: VGPR=52, FETCH=4.9GB, 22ms).
//
// 256 LSTM WGs (256 thr, 4 waves). Pair (g, g+128) shares batch group g
// (BPW=2); half = wg>>7 owns units [64h, 64h+64) -> 256 of 512 gate cols.
// 128 MFMA/WG-tick (621 cyc pipe floor, half of v9). Cross-WG h-exchange
// (512B packed f16) via L2, flag-gated device-scope atomics; the partner
// wait spins under the own-kt MFMA shadow. Exchange slots live in the tail
// of the zeros output, re-zeroed at exit after a reader-ack handshake.
// Blocks 256..511 fill the rest of the zeros output.
//
// d_out (f32): [0,32768) h2_final | [32768,+33554432) zeros | [33587200,..) c1

typedef _Float16 f16;
typedef _Float16 f16x2 __attribute__((ext_vector_type(2)));
typedef _Float16 f16x8 __attribute__((ext_vector_type(8)));
typedef float    f32x4 __attribute__((ext_vector_type(4)));

#define T_STEPS 1024
#define UNITS   128
#define NLSTM   256
#define NBLK    512
#define OUT_ZERO 32768
#define OUT_C1   33587200
#define TILEB   4096
#define ZTOT_F   33554432u
#define EXCH_DW  65536u                      // 256 WGs * 2 slots * 128 dwords
#define ZFILL_F4 ((ZTOT_F - EXCH_DW) / 4)

#define MFMA16(A,B,C) __builtin_amdgcn_mfma_f32_16x16x32_f16((A),(B),(C),0,0,0)

__device__ __forceinline__ float frcp_(float x) {
#if __has_builtin(__builtin_amdgcn_rcpf)
    return __builtin_amdgcn_rcpf(x);
#else
    return 1.0f / x;
#endif
}
__device__ __forceinline__ float sigmoidf_(float x) { return frcp_(1.0f + __expf(-x)); }
__device__ __forceinline__ float tanhf_(float x) {
    float e = __expf(2.0f * x);
    return 1.0f - 2.0f * frcp_(e + 1.0f);
}
__device__ __forceinline__ unsigned pkh(float a, float b) {
    f16x2 t; t[0] = (f16)a; t[1] = (f16)b;
    return __builtin_bit_cast(unsigned, t);
}
__device__ __forceinline__ int swb(int row, int byteoff) {
    return row * 256 + (byteoff ^ ((row & 7) << 4));
}

__global__ __launch_bounds__(256, 2) void lstm2_kernel(
    const float* __restrict__ X,   // [256][1024][128]
    const float* __restrict__ W,   // [128][512] gate order i|f|g|o
    const float* __restrict__ U,   // [128][512]
    const float* __restrict__ Bv,  // [512]
    float* __restrict__ out,
    int* __restrict__ flags)       // d_ws: [0..256) tick flags, [256..512) acks
{
    const int blk = blockIdx.x;
    const int tid = threadIdx.x;

    if (blk >= NLSTM) {
        // ---------- zeros-output fill (excluding the exchange tail) ----------
        const size_t nthr = (size_t)(NBLK - NLSTM) * 256;
        float4* dst = (float4*)(out + OUT_ZERO);
        const float4 z4 = make_float4(0.f, 0.f, 0.f, 0.f);
        for (size_t i = (size_t)(blk - NLSTM) * 256 + tid; i < ZFILL_F4; i += nthr)
            dst[i] = z4;
        return;
    }

    // ---------- LSTM workgroup ----------
    const int wg = blk, grp = wg & 127, half = wg >> 7, pwg = wg ^ 128;
    if (tid == 0) {   // reset own sync words first thing (stale-value safety)
        __hip_atomic_store(&flags[wg],       0, __ATOMIC_RELAXED, __HIP_MEMORY_SCOPE_AGENT);
        __hip_atomic_store(&flags[256 + wg], 0, __ATOMIC_RELAXED, __HIP_MEMORY_SCOPE_AGENT);
    }
    const int w  = tid >> 6;
    const int l  = tid & 63;
    const int lr = l & 15;
    const int lc = l >> 4;
    const int u  = half * 64 + w * 16 + lr;   // absolute unit (own col block)
    const int b0 = grp * 2;
    unsigned* exch = (unsigned*)(out + OUT_ZERO + (ZTOT_F - EXCH_DW));

    __shared__ __align__(16) char A1t[2][TILEB];   // rows 4a+0=x, 4a+1=h1
    __shared__ __align__(16) char A2t[2][TILEB];   // rows 4a+0=h1, 4a+1=h2
    char* A1base = &A1t[0][0];
    char* A2base = &A2t[0][0];

    // ---- K-slice permutation: local j=0,1 own half; j=2,3 partner half.
    //      (runtime VALUES in addresses; all ARRAY indices below are literal)
    const int h2o = half * 2;
    const int gkk[4] = {h2o, h2o + 1, h2o ^ 2, (h2o ^ 2) + 1};

    // ---- weight B-fragments: Wf[g][j], 8 f16 each — constant indices only
    f16x8 Wf[4][4], Uf[4][4];
    #pragma unroll
    for (int j = 0; j < 4; ++j) {
        const int kb = gkk[j] * 32 + lc * 8;
        #pragma unroll
        for (int g = 0; g < 4; ++g) {
            f16x8 wt, ut;
            #pragma unroll
            for (int jj = 0; jj < 8; ++jj) {
                const int krow = kb + jj;
                wt[jj] = (f16)W[(size_t)krow * 512 + g * 128 + u];
                ut[jj] = (f16)U[(size_t)krow * 512 + g * 128 + u];
            }
            Wf[g][j] = wt;  Uf[g][j] = ut;
        }
    }
    float bias[4];
    #pragma unroll
    for (int g = 0; g < 4; ++g) bias[g] = Bv[g * 128 + u];

    int raddr[4];
    #pragma unroll
    for (int j = 0; j < 4; ++j) raddr[j] = swb(lr, gkk[j] * 64 + lc * 16);

    // ---- init: zero tiles; x(0) -> A1 buf0 rows {0,4}
    for (int i = tid; i < 2 * TILEB / 4; i += 256) {
        ((float*)A1base)[i] = 0.0f;
        ((float*)A2base)[i] = 0.0f;
    }
    __syncthreads();
    if (tid < 128) {
        const int a = tid >> 6, c = (tid & 63) * 2;
        const float2 v = *(const float2*)(X + (size_t)(b0 + a) * (T_STEPS * UNITS) + c);
        *(unsigned*)(A1base + swb(4 * a, c * 2)) = pkh(v.x, v.y);
    }
    __syncthreads();

    float c1 = 0.f, c2 = 0.f;

    for (int k = 0; k <= T_STEPS; ++k) {
        const int rdo = (k & 1) * TILEB, wro = TILEB - rdo;
        char* A1r = A1base + rdo;  char* A1w = A1base + wro;
        char* A2r = A2base + rdo;  char* A2w = A2base + wro;

        // x(k+1) prefetch
        float xa = 0.f, xb = 0.f;
        const bool ldx = (tid < 128) && (k + 1 < T_STEPS);
        if (ldx) {
            const float2 v = *(const float2*)(X + (size_t)(b0 + (tid >> 6)) * (T_STEPS * UNITS)
                                                + (size_t)(k + 1) * UNITS + (tid & 63) * 2);
            xa = v.x; xb = v.y;
        }

        // ---- own-kt A fragments (local 0,1)
        f16x8 A1a0 = *(const f16x8*)(A1r + raddr[0]);
        f16x8 A1a1 = *(const f16x8*)(A1r + raddr[1]);
        f16x8 A2a0 = *(const f16x8*)(A2r + raddr[0]);
        f16x8 A2a1 = *(const f16x8*)(A2r + raddr[1]);

        // ---- phase C: 16 MFMA over own k-slices (ILP4)
        f32x4 accI = {bias[0], bias[0], bias[0], bias[0]};
        f32x4 accF = {bias[1], bias[1], bias[1], bias[1]};
        f32x4 accG = {bias[2], bias[2], bias[2], bias[2]};
        f32x4 accO = {bias[3], bias[3], bias[3], bias[3]};
        accI = MFMA16(A1a0, Wf[0][0], accI);  accF = MFMA16(A1a0, Wf[1][0], accF);
        accG = MFMA16(A1a0, Wf[2][0], accG);  accO = MFMA16(A1a0, Wf[3][0], accO);
        accI = MFMA16(A1a1, Wf[0][1], accI);  accF = MFMA16(A1a1, Wf[1][1], accF);
        accG = MFMA16(A1a1, Wf[2][1], accG);  accO = MFMA16(A1a1, Wf[3][1], accO);
        accI = MFMA16(A2a0, Uf[0][0], accI);  accF = MFMA16(A2a0, Uf[1][0], accF);
        accG = MFMA16(A2a0, Uf[2][0], accG);  accO = MFMA16(A2a0, Uf[3][0], accO);
        accI = MFMA16(A2a1, Uf[0][1], accI);  accF = MFMA16(A2a1, Uf[1][1], accF);
        accG = MFMA16(A2a1, Uf[2][1], accG);  accO = MFMA16(A2a1, Uf[3][1], accO);

        // ---- partner fetch (spin hides under the MFMA shadow)
        unsigned pd = 0;
        if (k > 0) {
            while (__hip_atomic_load(&flags[pwg], __ATOMIC_ACQUIRE, __HIP_MEMORY_SCOPE_AGENT) < k)
                __builtin_amdgcn_s_sleep(1);
            if (tid < 128)
                pd = exch[(size_t)pwg * 256 + (size_t)((k - 1) & 1) * 128 + tid];
        }
        // ---- phase D: partner h -> READ tiles (partner-unit bytes only)
        if (k > 0 && tid < 128) {
            const int a = tid >> 6, pu = (half ^ 1) * 64 + (tid & 63);
            const unsigned short h1b = (unsigned short)(pd & 0xffffu);
            const unsigned short h2b = (unsigned short)(pd >> 16);
            *(unsigned short*)(A1r + swb(4 * a + 1, pu * 2)) = h1b;
            *(unsigned short*)(A2r + swb(4 * a,     pu * 2)) = h1b;
            *(unsigned short*)(A2r + swb(4 * a + 1, pu * 2)) = h2b;
        }
        __syncthreads();
        if (k > 0 && tid == 0)   // reader-ack: partner slot (k-1) consumed
            __hip_atomic_store(&flags[256 + wg], k, __ATOMIC_RELEASE, __HIP_MEMORY_SCOPE_AGENT);

        // ---- partner-kt fragments (local 2,3)
        f16x8 A1b0 = *(const f16x8*)(A1r + raddr[2]);
        f16x8 A1b1 = *(const f16x8*)(A1r + raddr[3]);
        f16x8 A2b0 = *(const f16x8*)(A2r + raddr[2]);
        f16x8 A2b1 = *(const f16x8*)(A2r + raddr[3]);

        // ---- phase F: g,o finish first, then i,f with trans spliced
        accG = MFMA16(A1b0, Wf[2][2], accG);  accO = MFMA16(A1b0, Wf[3][2], accO);
        accG = MFMA16(A1b1, Wf[2][3], accG);  accO = MFMA16(A1b1, Wf[3][3], accO);
        accG = MFMA16(A2b0, Uf[2][2], accG);  accO = MFMA16(A2b0, Uf[3][2], accO);
        accG = MFMA16(A2b1, Uf[2][3], accG);  accO = MFMA16(A2b1, Uf[3][3], accO);
        float gg0, gg1, oo0, oo1;
        accI = MFMA16(A1b0, Wf[0][2], accI);  accF = MFMA16(A1b0, Wf[1][2], accF);
        gg0 = tanhf_(accG[0]);
        accI = MFMA16(A1b1, Wf[0][3], accI);  accF = MFMA16(A1b1, Wf[1][3], accF);
        oo0 = sigmoidf_(accO[0]);
        accI = MFMA16(A2b0, Uf[0][2], accI);  accF = MFMA16(A2b0, Uf[1][2], accF);
        gg1 = tanhf_(accG[1]);
        accI = MFMA16(A2b1, Uf[0][3], accI);  accF = MFMA16(A2b1, Uf[1][3], accF);
        oo1 = sigmoidf_(accO[1]);

        // ---- tail: e=0 cell1 step k, e=1 cell2 step k-1
        const bool act1 = (k < T_STEPS), act2 = (k > 0);
        const float si0 = sigmoidf_(accI[0]), si1 = sigmoidf_(accI[1]);
        const float sf0 = sigmoidf_(accF[0]), sf1 = sigmoidf_(accF[1]);
        const float cn1 = sf0 * c1 + si0 * gg0;
        const float cn2 = sf1 * c2 + si1 * gg1;
        if (act1) c1 = cn1;
        if (act2) c2 = cn2;
        const float h1v = oo0 * tanhf_(cn1);
        const float h2v = act2 ? (oo1 * tanhf_(cn2)) : 0.0f;

        // ---- own h writes + exchange publish + final outputs
        if (lc < 2) {
            if (act1) {
                *(f16*)(A1w + swb(4 * lc + 1, u * 2)) = (f16)h1v;
                *(f16*)(A2w + swb(4 * lc,     u * 2)) = (f16)h1v;
            }
            if (act1 && act2)
                *(f16*)(A2w + swb(4 * lc + 1, u * 2)) = (f16)h2v;
            if (k < T_STEPS)
                exch[(size_t)wg * 256 + (size_t)(k & 1) * 128 + lc * 64 + w * 16 + lr] = pkh(h1v, h2v);
            if (k == T_STEPS - 1) out[OUT_C1 + (size_t)(b0 + lc) * UNITS + u] = c1;
            if (k == T_STEPS)     out[(size_t)(b0 + lc) * UNITS + u] = h2v;
        }
        if (ldx)
            *(unsigned*)(A1w + swb(4 * (tid >> 6), (tid & 63) * 4)) = pkh(xa, xb);

        __syncthreads();
        if (k < T_STEPS && tid == 0)   // publish h(k)
            __hip_atomic_store(&flags[wg], k + 1, __ATOMIC_RELEASE, __HIP_MEMORY_SCOPE_AGENT);
    }

    // ---- exit: wait until partner consumed our last slot, then zero our
    //      exchange words (they live inside the validated zeros region)
    while (__hip_atomic_load(&flags[256 + pwg], __ATOMIC_ACQUIRE, __HIP_MEMORY_SCOPE_AGENT) < T_STEPS)
        __builtin_amdgcn_s_sleep(1);
    exch[(size_t)wg * 256 + tid] = 0;
}

extern "C" void kernel_launch(void* const* d_in, const int* in_sizes, int n_in,
                              void* d_out, int out_size, void* d_ws, size_t ws_size,
                              hipStream_t stream) {
    const float* X  = (const float*)d_in[0];
    const float* W  = (const float*)d_in[1];
    const float* U  = (const float*)d_in[2];
    const float* Bv = (const float*)d_in[3];
    float* out = (float*)d_out;
    int* flags = (int*)d_ws;   // 2 KiB used
    hipLaunchKernelGGL(lstm2_kernel, dim3(NBLK), dim3(256), 0, stream,
                       X, W, U, Bv, out, flags);
}

// Round 15
// 997.054 us; speedup vs baseline: 22.1011x; 19.6899x over previous
//
#include <hip/hip_runtime.h>

// 2-layer stacked LSTM (shared cell), B=256, T=1024, F=UNITS=128 — MFMA v11.
// = v9 (996us, 64 WGs x BPW=4, cell-interleaved M) with a single overlapped
//   A-tile: rows 4a+0=x_a, 4a+1=h1_a, 4a+2=h2_a, 4a+3=pad (17 rows alloc'd).
//   A1 reads row lr, A2 reads row lr+1:
//     C row 4a+0: x@W + h1@U = z1_a ;  C row 4a+1: h1@W + h2@U = z2_a.
//   h1 written ONCE (vs twice in v9's two-tile layout), LDS 2x4.25KB.
// Schedule = proven v5 splice: g,o chains (ILP2) -> i,f chains with
// tanh(g)/sigma(o)/x-write spliced -> short tail. One barrier per tick.
// Blocks 64..255 fill the zeros output.
//
// d_out (f32): [0,32768) h2_final | [32768,+33554432) zeros | [33587200,..) c1

typedef _Float16 f16;
typedef _Float16 f16x2 __attribute__((ext_vector_type(2)));
typedef _Float16 f16x8 __attribute__((ext_vector_type(8)));
typedef float    f32x4 __attribute__((ext_vector_type(4)));

#define T_STEPS 1024
#define UNITS   128
#define NLSTM   64
#define BPW     4
#define NBLK    256
#define OUT_ZERO 32768
#define OUT_C1   33587200
#define TILEB   4352   // 17 rows * 256B (row 16 = read-only junk for lr=15 A2)

#define MFMA16(A,B,C) __builtin_amdgcn_mfma_f32_16x16x32_f16((A),(B),(C),0,0,0)

__device__ __forceinline__ float frcp_(float x) {
#if __has_builtin(__builtin_amdgcn_rcpf)
    return __builtin_amdgcn_rcpf(x);
#else
    return 1.0f / x;
#endif
}
__device__ __forceinline__ float sigmoidf_(float x) { return frcp_(1.0f + __expf(-x)); }
__device__ __forceinline__ float tanhf_(float x) {
    float e = __expf(2.0f * x);
    return 1.0f - 2.0f * frcp_(e + 1.0f);
}
__device__ __forceinline__ unsigned pkh(float a, float b) {
    f16x2 t; t[0] = (f16)a; t[1] = (f16)b;
    return __builtin_bit_cast(unsigned, t);
}
// swizzled byte address within the 17-row x 256B tile (XOR 16B slot by row&7)
__device__ __forceinline__ int swb(int row, int byteoff) {
    return row * 256 + (byteoff ^ ((row & 7) << 4));
}

__global__ __launch_bounds__(512, 2) void lstm2_kernel(
    const float* __restrict__ X,   // [256][1024][128]
    const float* __restrict__ W,   // [128][512] gate order i|f|g|o
    const float* __restrict__ U,   // [128][512]
    const float* __restrict__ Bv,  // [512]
    float* __restrict__ out)
{
    const int blk = blockIdx.x;
    const int tid = threadIdx.x;

    if (blk >= NLSTM) {
        // ---------- zeros-output fill on idle CUs ----------
        const size_t nthr = (size_t)(NBLK - NLSTM) * 512;
        float4* dst = (float4*)(out + OUT_ZERO);
        const float4 z4 = make_float4(0.f, 0.f, 0.f, 0.f);
        for (size_t i = (size_t)(blk - NLSTM) * 512 + tid; i < 8388608u; i += nthr)
            dst[i] = z4;
        return;
    }

    // ---------- LSTM workgroup ----------
    const int w  = tid >> 6;        // wave = unit block [16w,16w+16)
    const int l  = tid & 63;
    const int lr = l & 15;          // A row-in-tile / C col (unit in block)
    const int lc = l >> 4;          // k-sub / owned batch row
    const int u  = w * 16 + lr;     // unit in [0,128)
    const int b0 = blk * BPW;

    __shared__ __align__(16) char Ab[2][TILEB];
    char* Abase = &Ab[0][0];

    // ---- weight B-fragments (resident): [gate][ktile], 8 f16 each
    f16x8 Wf[4][4], Uf[4][4];
    #pragma unroll
    for (int g = 0; g < 4; ++g) {
        #pragma unroll
        for (int kt = 0; kt < 4; ++kt) {
            f16x8 wt, ut;
            #pragma unroll
            for (int j = 0; j < 8; ++j) {
                const int krow = kt * 32 + lc * 8 + j;
                wt[j] = (f16)W[(size_t)krow * 512 + g * 128 + u];
                ut[j] = (f16)U[(size_t)krow * 512 + g * 128 + u];
            }
            Wf[g][kt] = wt;  Uf[g][kt] = ut;
        }
    }
    float bias[4];
    #pragma unroll
    for (int g = 0; g < 4; ++g) bias[g] = Bv[g * 128 + u];

    // ---- lane-constant addresses
    int ard1[4], ard2[4];
    #pragma unroll
    for (int kt = 0; kt < 4; ++kt) {
        ard1[kt] = swb(lr,     kt * 64 + lc * 16);
        ard2[kt] = swb(lr + 1, kt * 64 + lc * 16);
    }
    const int wh1 = swb(4 * lc + 1, u * 2);
    const int wh2 = swb(4 * lc + 2, u * 2);

    // ---- init: zero both buffers (pad rows stay zero); x(0) -> buf0 rows 4a
    for (int i = tid; i < 2 * TILEB / 4; i += 512) ((float*)Abase)[i] = 0.0f;
    __syncthreads();
    if (tid < 256) {
        const int a = tid >> 6, uc = (tid & 63) * 2;
        const float2 xv = *(const float2*)(X + (size_t)(b0 + a) * (T_STEPS * UNITS) + uc);
        *(unsigned*)(Abase + swb(4 * a, uc * 2)) = pkh(xv.x, xv.y);
    }
    __syncthreads();

    float c1 = 0.f, c2 = 0.f;

    for (int k = 0; k <= T_STEPS; ++k) {
        const int rdo = (k & 1) * TILEB, wro = TILEB - rdo;
        char* Ar = Abase + rdo;
        char* Aw = Abase + wro;

        // x(k+1) prefetch (in flight under the MFMA phase)
        float xa = 0.f, xb = 0.f; int xrow = 0, xuc = 0;
        const bool ldx = (tid < 256) && (k + 1 < T_STEPS);
        if (ldx) {
            const int a = tid >> 6; xuc = (tid & 63) * 2; xrow = 4 * a;
            const float2 xv = *(const float2*)(X + (size_t)(b0 + a) * (T_STEPS * UNITS)
                                                 + (size_t)(k + 1) * UNITS + xuc);
            xa = xv.x; xb = xv.y;
        }

        // ---- A fragments (single tile, rows lr and lr+1)
        f16x8 A1[4], A2[4];
        #pragma unroll
        for (int kt = 0; kt < 4; ++kt) {
            A1[kt] = *(const f16x8*)(Ar + ard1[kt]);
            A2[kt] = *(const f16x8*)(Ar + ard2[kt]);
        }

        // ---- P1: g,o chains (16 MFMA, ILP2)
        f32x4 accg = {bias[2], bias[2], bias[2], bias[2]};
        f32x4 acco = {bias[3], bias[3], bias[3], bias[3]};
        #pragma unroll
        for (int kt = 0; kt < 4; ++kt) {
            accg = MFMA16(A1[kt], Wf[2][kt], accg);
            acco = MFMA16(A1[kt], Wf[3][kt], acco);
        }
        #pragma unroll
        for (int kt = 0; kt < 4; ++kt) {
            accg = MFMA16(A2[kt], Uf[2][kt], accg);
            acco = MFMA16(A2[kt], Uf[3][kt], acco);
        }

        // ---- P2: i,f chains with g/o trans + x-write spliced (dep-free)
        f32x4 acci = {bias[0], bias[0], bias[0], bias[0]};
        f32x4 accf = {bias[1], bias[1], bias[1], bias[1]};
        float gg0, gg1, oo0, oo1;
        acci = MFMA16(A1[0], Wf[0][0], acci);  accf = MFMA16(A1[0], Wf[1][0], accf);
        gg0 = tanhf_(accg[0]);
        acci = MFMA16(A1[1], Wf[0][1], acci);  accf = MFMA16(A1[1], Wf[1][1], accf);
        oo0 = sigmoidf_(acco[0]);
        acci = MFMA16(A1[2], Wf[0][2], acci);  accf = MFMA16(A1[2], Wf[1][2], accf);
        gg1 = tanhf_(accg[1]);
        acci = MFMA16(A1[3], Wf[0][3], acci);  accf = MFMA16(A1[3], Wf[1][3], accf);
        oo1 = sigmoidf_(acco[1]);
        acci = MFMA16(A2[0], Uf[0][0], acci);  accf = MFMA16(A2[0], Uf[1][0], accf);
        if (ldx)   // x(k+1) -> write buffer row 4a
            *(unsigned*)(Aw + swb(xrow, xuc * 2)) = pkh(xa, xb);
        acci = MFMA16(A2[1], Uf[0][1], acci);  accf = MFMA16(A2[1], Uf[1][1], accf);
        acci = MFMA16(A2[2], Uf[0][2], acci);  accf = MFMA16(A2[2], Uf[1][2], accf);
        acci = MFMA16(A2[3], Uf[0][3], acci);  accf = MFMA16(A2[3], Uf[1][3], accf);

        // ---- tail: two independent chains (cell1 e=0, cell2 e=1)
        const bool act1 = (k < T_STEPS), act2 = (k > 0);
        const float si0 = sigmoidf_(acci[0]);
        const float si1 = sigmoidf_(acci[1]);
        const float sf0 = sigmoidf_(accf[0]);
        const float sf1 = sigmoidf_(accf[1]);
        const float cn1 = sf0 * c1 + si0 * gg0;
        const float cn2 = sf1 * c2 + si1 * gg1;
        if (act1) c1 = cn1;
        if (act2) c2 = cn2;
        const float h1v = oo0 * tanhf_(cn1);
        const float h2v = act2 ? (oo1 * tanhf_(cn2)) : 0.0f;

        // ---- h writes (single placement each)
        if (act1)
            *(f16*)(Aw + wh1) = (f16)h1v;            // row 4lc+1
        if (act1 && act2)
            *(f16*)(Aw + wh2) = (f16)h2v;            // row 4lc+2

        // ---- final outputs
        if (k == T_STEPS - 1)
            out[OUT_C1 + (size_t)(b0 + lc) * UNITS + u] = c1;
        if (k == T_STEPS)
            out[(size_t)(b0 + lc) * UNITS + u] = h2v;
        __syncthreads();
    }
}

extern "C" void kernel_launch(void* const* d_in, const int* in_sizes, int n_in,
                              void* d_out, int out_size, void* d_ws, size_t ws_size,
                              hipStream_t stream) {
    const float* X  = (const float*)d_in[0];
    const float* W  = (const float*)d_in[1];
    const float* U  = (const float*)d_in[2];
    const float* Bv = (const float*)d_in[3];
    float* out = (float*)d_out;
    hipLaunchKernelGGL(lstm2_kernel, dim3(NBLK), dim3(512), 0, stream,
                       X, W, U, Bv, out);
}